// Round 4
// baseline (461.025 us; speedup 1.0000x reference)
//
#include <hip/hip_runtime.h>

#define NH 4
#define HD 128
#define BS 32
#define STRIDE 16
#define JSPLIT 2
#define JR (BS / JSPLIT)   // 16 j's per block

typedef float  floatx4 __attribute__((ext_vector_type(4)));
typedef __bf16 bf16x8  __attribute__((ext_vector_type(8)));
typedef unsigned short u16x8 __attribute__((ext_vector_type(8)));
typedef unsigned int u32x4 __attribute__((ext_vector_type(4)));

__device__ __forceinline__ unsigned short f2bf(float f) {
  unsigned u = __builtin_bit_cast(unsigned, f);
  u += 0x7FFFu + ((u >> 16) & 1u);   // RTNE — used only in prep (off hot path)
  return (unsigned short)(u >> 16);
}

// Truncating f32x8 -> bf16x8 via v_perm_b32: 4 VALU instructions total.
// perm(src0=f1, src1=f0, 0x07060302) packs {bf16(f1)<<16 | bf16(f0)}.
__device__ __forceinline__ bf16x8 cvt8(float4 lo, float4 hi) {
  u32x4 w;
  w[0] = __builtin_amdgcn_perm(__builtin_bit_cast(unsigned, lo.y),
                               __builtin_bit_cast(unsigned, lo.x), 0x07060302u);
  w[1] = __builtin_amdgcn_perm(__builtin_bit_cast(unsigned, lo.w),
                               __builtin_bit_cast(unsigned, lo.z), 0x07060302u);
  w[2] = __builtin_amdgcn_perm(__builtin_bit_cast(unsigned, hi.y),
                               __builtin_bit_cast(unsigned, hi.x), 0x07060302u);
  w[3] = __builtin_amdgcn_perm(__builtin_bit_cast(unsigned, hi.w),
                               __builtin_bit_cast(unsigned, hi.z), 0x07060302u);
  return __builtin_bit_cast(bf16x8, w);
}

__device__ __forceinline__ void gld16(const unsigned short* g, unsigned short* l) {
  __builtin_amdgcn_global_load_lds(
      (const __attribute__((address_space(1))) unsigned int*)(g),
      (__attribute__((address_space(3))) unsigned int*)(l), 16, 0, 0);
}

// Prep: LDS-tiled transpose of w into wt layout [mat][j][k0][fq][e][dq] (bf16).
// Last block writes the cu_out prefix-sum tail (output 2).
__global__ void prep_kernel(const float* __restrict__ wk, const float* __restrict__ wv,
                            unsigned short* __restrict__ wt,
                            const int* __restrict__ cu, int num_seqs,
                            float* __restrict__ tail) {
  const int bx = blockIdx.x;
  if (bx == 2 * BS * 4) {
    if (threadIdx.x == 0) {
      int acc = 0;
      tail[0] = 0.0f;
      for (int b = 0; b < num_seqs; ++b) {
        int n = cu[b + 1] - cu[b];
        acc += (n - BS) / STRIDE;
        tail[b + 1] = (float)acc;
      }
    }
    return;
  }
  const int mat = bx >> 7;
  const int j   = (bx >> 2) & 31;
  const int k0  = bx & 3;
  const float* __restrict__ w =
      (mat ? wv : wk) + (size_t)j * (HD * HD) + (size_t)k0 * 32 * HD;
  __shared__ unsigned short tile[32][HD];
  const int t = threadIdx.x;
  const int r = t >> 3, c = (t & 7) * 16;
#pragma unroll
  for (int i = 0; i < 16; i += 4) {
    float4 f = *(const float4*)(w + r * HD + c + i);
    tile[r][c + i + 0] = f2bf(f.x);
    tile[r][c + i + 1] = f2bf(f.y);
    tile[r][c + i + 2] = f2bf(f.z);
    tile[r][c + i + 3] = f2bf(f.w);
  }
  __syncthreads();
  unsigned short* dst =
      wt + (size_t)mat * (BS * HD * HD) + (size_t)j * 16384 + k0 * 4096;
#pragma unroll
  for (int it = 0; it < 2; ++it) {
    int fi = t + it * 256;      // 0..511 over (fq, e)
    int fq = fi >> 7, e = fi & 127;
    u16x8 fr;
#pragma unroll
    for (int dq = 0; dq < 8; ++dq) fr[dq] = tile[fq * 8 + dq][e];
    *(u16x8*)(dst + fq * 1024 + e * 8) = fr;
  }
}

// Zero the GEMM output region (atomicAdd accumulates into it).
__global__ void zero_out(float* __restrict__ out, long n4) {
  const long stride = (long)gridDim.x * blockDim.x;
  float4 z = {0.f, 0.f, 0.f, 0.f};
  for (long i = blockIdx.x * blockDim.x + threadIdx.x; i < n4; i += stride)
    ((float4*)out)[i] = z;
}

// Main GEMM, split-K x2 over j. Block = 32m x 128n, 4 waves.
// B double-buffered in LDS via global_load_lds; A in registers (1-j prefetch);
// fp32 atomicAdd epilogue.
__global__ __launch_bounds__(256, 5) void kvc_gemm(
    const float* __restrict__ kp, const float* __restrict__ vp,
    const unsigned short* __restrict__ wt, const int* __restrict__ cu,
    float* __restrict__ out, long out_half, int M_total, int num_seqs) {

  __shared__ unsigned short Bs[2][8192];   // 2 x 16 KB stages

  const int mat = blockIdx.y;
  const int j0  = blockIdx.z * JR;
  const int jend = j0 + JR;
  const float* __restrict__ x = mat ? vp : kp;
  const unsigned short* __restrict__ wmat = wt + (size_t)mat * (BS * HD * HD);
  float* __restrict__ outp = out + (size_t)mat * out_half;

  const int tid = threadIdx.x, wid = tid >> 6, lane = tid & 63;
  const int fl = lane & 15, fq = lane >> 4;
  const int msub = (wid & 1) * 16;
  const int ehw  = (wid >> 1) * 64;
  const int mbase = blockIdx.x * 32 + msub;

  // m -> (o,h) -> token base
  int m = mbase + fl;
  int mc = m < M_total ? m : M_total - 1;
  int o = mc >> 2, h = mc & 3;
  int tb = 0, accb = 0;
  for (int b = 0; b < num_seqs; ++b) {
    int c0 = cu[b], c1 = cu[b + 1];
    int ol = (c1 - c0 - BS) / STRIDE;
    if (o >= accb && o - accb < ol) tb = c0 + (o - accb) * STRIDE;
    accb += ol;
  }
  const float* __restrict__ arow = x + ((size_t)tb * NH + h) * HD + fq * 8;

  floatx4 acc[4];
#pragma unroll
  for (int ni = 0; ni < 4; ++ni) acc[ni] = (floatx4){0.f, 0.f, 0.f, 0.f};

  float4 a[2][8];

#define ALOAD(JN, P)                                                        \
  {                                                                         \
    const float* ar_ = arow + (size_t)(JN) * (NH * HD);                     \
    _Pragma("unroll") for (int k0_ = 0; k0_ < 4; ++k0_) {                   \
      a[P][2 * k0_]     = *(const float4*)(ar_ + k0_ * 32);                 \
      a[P][2 * k0_ + 1] = *(const float4*)(ar_ + k0_ * 32 + 4);             \
    }                                                                       \
  }

#define BSTAGE(J, H, P)                                                     \
  {                                                                         \
    const unsigned short* s_ =                                              \
        wmat + (size_t)(J) * 16384 + (H) * 8192 + wid * 2048 + lane * 8;    \
    _Pragma("unroll") for (int i_ = 0; i_ < 4; ++i_)                        \
        gld16(s_ + i_ * 512, &Bs[P][wid * 2048 + i_ * 512]);                \
  }

#define CPH(PA, P, KB)                                                      \
  {                                                                         \
    _Pragma("unroll") for (int k0l_ = 0; k0l_ < 2; ++k0l_) {                \
      const int k0_ = (KB) + k0l_;                                          \
      bf16x8 af_ = cvt8(a[PA][2 * k0_], a[PA][2 * k0_ + 1]);                \
      _Pragma("unroll") for (int ni_ = 0; ni_ < 4; ++ni_) {                 \
        bf16x8 bf_ = *(const bf16x8*)&Bs[P][k0l_ * 4096 + fq * 1024 +       \
                                           (ehw + ni_ * 16 + fl) * 8];      \
        acc[ni_] = __builtin_amdgcn_mfma_f32_16x16x32_bf16(                 \
            af_, bf_, acc[ni_], 0, 0, 0);                                   \
      }                                                                     \
    }                                                                       \
  }

#define JBODY(J, PA)                                                        \
  {                                                                         \
    __syncthreads();              /* (J,h0) staged into buf0 is ready */    \
    BSTAGE(J, 1, 1);              /* stage (J,h1) -> buf1 */                \
    if ((J) + 1 < jend) ALOAD((J) + 1, PA ^ 1);                             \
    CPH(PA, 0, 0);                                                          \
    __syncthreads();              /* (J,h1) ready */                        \
    if ((J) + 1 < jend) BSTAGE((J) + 1, 0, 0);  /* (J+1,h0) -> buf0 */      \
    CPH(PA, 1, 2);                                                          \
  }

  BSTAGE(j0, 0, 0);
  ALOAD(j0, 0);
  for (int j = j0; j < jend; j += 2) {
    JBODY(j, 0);
    JBODY(j + 1, 1);
  }
#undef JBODY
#undef CPH
#undef BSTAGE
#undef ALOAD

  // C/D: col = lane&15 (= e offset fl), row = fq*4 + reg. Accumulate split-K.
#pragma unroll
  for (int ni = 0; ni < 4; ++ni) {
#pragma unroll
    for (int r = 0; r < 4; ++r) {
      const int mg = mbase + fq * 4 + r;
      if (mg < M_total)
        atomicAdd(&outp[(size_t)mg * HD + ehw + ni * 16 + fl], acc[ni][r]);
    }
  }
}

// Fallback path if ws is too small for the weight transpose.
__global__ void tail_kernel(const int* __restrict__ cu, int num_seqs,
                            float* __restrict__ tail) {
  if (threadIdx.x == 0) {
    int acc = 0;
    tail[0] = 0.0f;
    for (int b = 0; b < num_seqs; ++b) {
      int n = cu[b + 1] - cu[b];
      acc += (n - BS) / STRIDE;
      tail[b + 1] = (float)acc;
    }
  }
}

__global__ void kvc_naive(const float* __restrict__ kp, const float* __restrict__ vp,
                          const float* __restrict__ wk, const float* __restrict__ wv,
                          const int* __restrict__ cu, int num_seqs,
                          float* __restrict__ out, long out_half) {
  int o = blockIdx.x, h = blockIdx.y, mat = blockIdx.z;
  int e = threadIdx.x;
  int acc = 0, base = -1;
  for (int b = 0; b < num_seqs; ++b) {
    int n = cu[b + 1] - cu[b];
    int ol = (n - BS) / STRIDE;
    if (o < acc + ol) { base = cu[b] + (o - acc) * STRIDE; break; }
    acc += ol;
  }
  if (base < 0) return;
  const float* x = mat ? vp : kp;
  const float* w = mat ? wv : wk;
  float s = 0.f;
  for (int j = 0; j < BS; ++j)
    for (int d = 0; d < HD; ++d)
      s += x[(size_t)(base + j) * (NH * HD) + h * HD + d] * w[(j * HD + d) * HD + e];
  out[(size_t)mat * out_half + ((size_t)o * NH + h) * HD + e] = s;
}

extern "C" void kernel_launch(void* const* d_in, const int* in_sizes, int n_in,
                              void* d_out, int out_size, void* d_ws, size_t ws_size,
                              hipStream_t stream) {
  const float* kp = (const float*)d_in[0];
  const float* vp = (const float*)d_in[1];
  const float* wk = (const float*)d_in[2];
  const float* wv = (const float*)d_in[3];
  const int* cu = (const int*)d_in[4];
  const int num_seqs = in_sizes[4] - 1;
  float* out = (float*)d_out;

  const long total_out = ((long)out_size - (num_seqs + 1)) / (2L * NH * HD);
  const long out_half = total_out * NH * HD;
  const int M_total = (int)(total_out * NH);
  float* tail = out + 2 * out_half;

  const size_t need_ws = (size_t)2 * BS * HD * HD * sizeof(unsigned short);
  if (ws_size >= need_ws) {
    unsigned short* wt = (unsigned short*)d_ws;
    prep_kernel<<<2 * BS * 4 + 1, 256, 0, stream>>>(wk, wv, wt, cu, num_seqs, tail);
    zero_out<<<1024, 256, 0, stream>>>(out, (2 * out_half) / 4);
    dim3 grid((M_total + 31) / 32, 2, JSPLIT);
    kvc_gemm<<<grid, 256, 0, stream>>>(kp, vp, wt, cu, out, out_half, M_total,
                                       num_seqs);
  } else {
    tail_kernel<<<1, 64, 0, stream>>>(cu, num_seqs, tail);
    dim3 grid((unsigned)total_out, NH, 2);
    kvc_naive<<<grid, HD, 0, stream>>>(kp, vp, wk, wv, cu, num_seqs, out, out_half);
  }
}